// Round 28
// baseline (228.106 us; speedup 1.0000x reference)
//
#include <hip/hip_runtime.h>
#include <hip/hip_bf16.h>
#include <cstdint>

#define DIN 256
#define DH 128
#define DOUT 32
#define CE 4096          // edges per partition block (multiple of 256)
#define BSH 9            // bucket = 512-node window
#define MAXW 12288       // max adj window ints staged in LDS (48 KB)

typedef short s16x8 __attribute__((ext_vector_type(8)));
typedef float f32x4 __attribute__((ext_vector_type(4)));

__device__ inline ushort f2bf(float f) {          // used only in tiny prep
    uint u = __float_as_uint(f);
    u += 0x7fff + ((u >> 16) & 1);
    return (ushort)(u >> 16);
}
__device__ inline ushort cvtbf(float f) {         // compiler -> v_cvt_pk_bf16_f32
    __hip_bfloat16 b = __float2bfloat16(f);
    return __builtin_bit_cast(ushort, b);
}
__device__ inline float bf_lo(uint u) { return __uint_as_float(u << 16); }
__device__ inline float bf_hi(uint u) { return __uint_as_float(u & 0xffff0000u); }
__device__ inline uint packbf(float a, float b) {
    return (uint)cvtbf(a) | ((uint)cvtbf(b) << 16);
}
// compiler pattern-matches these to v_cvt_f32_ubyte0-3
__device__ inline float ub0(uint v) { return (float)(v & 0xFFu); }
__device__ inline float ub1(uint v) { return (float)((v >> 8) & 0xFFu); }
__device__ inline float ub2(uint v) { return (float)((v >> 16) & 0xFFu); }
__device__ inline float ub3(uint v) { return (float)(v >> 24); }

// ---------------- K1: part (blocks 0..nblk1-1)  ||  prep W1^T (last 32) ------

__global__ __launch_bounds__(256) void k_pre(
    const int* __restrict__ src, const int* __restrict__ dst,
    uint* __restrict__ pairs, int* __restrict__ tbl, int* __restrict__ gctr,
    const float* __restrict__ W1, ushort* __restrict__ w1tg,
    int e, int nbuck, int nblk1) {
    __shared__ int cnt[256];
    __shared__ int boffs[256];
    __shared__ int sh[256];
    __shared__ uint ps[CE];
    int tid = threadIdx.x;

    if (blockIdx.x >= nblk1) {   // ---- prep path: W1^T -> bf16 (64 KB)
        int o = (blockIdx.x - nblk1) * 1024 + tid * 4;
        int c = o >> 8;
        int k = o & 255;
        ushort4 v;
        v.x = f2bf(W1[(size_t)(k + 0) * DH + c]);
        v.y = f2bf(W1[(size_t)(k + 1) * DH + c]);
        v.z = f2bf(W1[(size_t)(k + 2) * DH + c]);
        v.w = f2bf(W1[(size_t)(k + 3) * DH + c]);
        *(ushort4*)(w1tg + o) = v;
        return;
    }

    // ---- part path: pack = (d&511)<<17 | s
    if (blockIdx.x == 0 && tid == 0) *gctr = 0;
    long blkbase = (long)blockIdx.x * CE;
    int ecnt = min(CE, (int)(e - blkbase));

    cnt[tid] = 0;
    __syncthreads();

    int dreg[CE / 256];
    #pragma unroll
    for (int k = 0; k < CE / 256; ++k) {
        int i = k * 256 + tid;
        int d = -1;
        if (i < ecnt) {
            d = dst[blkbase + i];
            atomicAdd(&cnt[d >> BSH], 1);
        }
        dreg[k] = d;
    }
    __syncthreads();
    sh[tid] = cnt[tid];
    __syncthreads();
    for (int off = 1; off < 256; off <<= 1) {
        int x = (tid >= off) ? sh[tid - off] : 0;
        __syncthreads();
        if (tid >= off) sh[tid] += x;
        __syncthreads();
    }
    boffs[tid] = (tid == 0) ? 0 : sh[tid - 1];
    cnt[tid] = 0;
    __syncthreads();
    #pragma unroll
    for (int k = 0; k < CE / 256; ++k) {
        int i = k * 256 + tid;
        if (i < ecnt) {
            int d = dreg[k];
            int b = d >> BSH;
            int slot = boffs[b] + atomicAdd(&cnt[b], 1);
            ps[slot] = ((uint)(d & 511) << 17) | (uint)src[blkbase + i];
        }
    }
    __syncthreads();
    for (int i = tid; i < ecnt; i += 256)
        pairs[blkbase + i] = ps[i];
    if (tid < nbuck) tbl[blockIdx.x * (nbuck + 1) + tid] = boffs[tid];
    if (tid == 0)    tbl[blockIdx.x * (nbuck + 1) + nbuck] = ecnt;
}

// ---------------- K2: gemm1 (blocks 0..ngemm-1)  ||  build (rest) ------------
// gemm1 quantizes h WITHOUT dis (scl = rowmax/127); k_fix multiplies dis in
// afterwards -> gemm1 no longer depends on build, so they overlap in one grid.
// Manual LDS union keeps the block at 54.3 KB -> 3 blocks/CU.

__global__ __launch_bounds__(256) void k_bg(
    const float* __restrict__ x, const ushort* __restrict__ w1tg,
    uchar* __restrict__ hs8, float* __restrict__ scl,
    const uint* __restrict__ pairs, const int* __restrict__ tbl,
    int* __restrict__ deg, int* __restrict__ offs, float* __restrict__ dis,
    int* __restrict__ adj, int* __restrict__ gctr,
    int nblk1, int nbuck, int n, int ngemm) {
    __shared__ __align__(16) char smem[54288];
    int tid = threadIdx.x;

    if (blockIdx.x < ngemm) {
        // ================= gemm1 path =================
        ushort (*w1t)[136] = (ushort(*)[136])smem;          // 34816 B
        uchar  (*cs8)[144] = (uchar(*)[144])smem;           // union
        ushort (*xs)[72]   = (ushort(*)[72])(smem + 34816); // 18432 B

        int row0 = blockIdx.x * 128;
        int lane = tid & 63;
        int w = tid >> 6;
        int wr0 = w * 32;
        int l15 = lane & 15;
        int koff = (lane >> 4) * 8;

        f32x4 acc[2][8];
        #pragma unroll
        for (int i = 0; i < 2; ++i)
            #pragma unroll
            for (int j = 0; j < 8; ++j)
                acc[i][j] = (f32x4){0.f, 0.f, 0.f, 0.f};

        for (int kh = 0; kh < 2; ++kh) {
            {   // stage w1t half: pure vector copy
                int c = tid >> 1;
                int seg = (tid & 1) * 64;
                const uint4* gsrc = (const uint4*)(w1tg + (size_t)c * 256 + kh * 128 + seg);
                uint4* ldst = (uint4*)&w1t[c][seg];
                #pragma unroll
                for (int q = 0; q < 8; ++q) ldst[q] = gsrc[q];
            }
            for (int kc2 = 0; kc2 < 2; ++kc2) {
                {   // stage x tile (fp32 -> bf16 HW cvt)
                    int r = tid >> 1;
                    int half = (tid & 1) * 32;
                    int rr = row0 + r; if (rr >= n) rr = n - 1;
                    const float4* xr = (const float4*)(x + (size_t)rr * DIN + kh * 128 + kc2 * 64 + half);
                    float4 v[8];
                    #pragma unroll
                    for (int q = 0; q < 8; ++q) v[q] = xr[q];
                    #pragma unroll
                    for (int q = 0; q < 8; ++q) {
                        ushort4 o;
                        o.x = cvtbf(v[q].x); o.y = cvtbf(v[q].y);
                        o.z = cvtbf(v[q].z); o.w = cvtbf(v[q].w);
                        *(ushort4*)&xs[r][half + q * 4] = o;
                    }
                }
                __syncthreads();
                #pragma unroll
                for (int kk = 0; kk < 64; kk += 32) {
                    s16x8 a0 = *(const s16x8*)&xs[wr0 + l15][kk + koff];
                    s16x8 a1 = *(const s16x8*)&xs[wr0 + 16 + l15][kk + koff];
                    int kl = kc2 * 64 + kk + koff;
                    #pragma unroll
                    for (int ct = 0; ct < 8; ++ct) {
                        s16x8 b = *(const s16x8*)&w1t[ct * 16 + l15][kl];
                        acc[0][ct] = __builtin_amdgcn_mfma_f32_16x16x32_bf16(a0, b, acc[0][ct], 0, 0, 0);
                        acc[1][ct] = __builtin_amdgcn_mfma_f32_16x16x32_bf16(a1, b, acc[1][ct], 0, 0, 0);
                    }
                }
                __syncthreads();
            }
        }

        // quantize per row (NO dis — folded in later by k_fix)
        #pragma unroll
        for (int rt = 0; rt < 2; ++rt) {
            #pragma unroll
            for (int r = 0; r < 4; ++r) {
                int lrow = wr0 + rt * 16 + (lane >> 4) * 4 + r;
                float vals[8];
                float mx = 0.f;
                #pragma unroll
                for (int ct = 0; ct < 8; ++ct) {
                    vals[ct] = acc[rt][ct][r];
                    mx = fmaxf(mx, fabsf(vals[ct]));
                }
                mx = fmaxf(mx, __shfl_xor(mx, 1));
                mx = fmaxf(mx, __shfl_xor(mx, 2));
                mx = fmaxf(mx, __shfl_xor(mx, 4));
                mx = fmaxf(mx, __shfl_xor(mx, 8));
                float s = mx * (1.f / 127.f);
                float inv = (mx > 0.f) ? 127.f / mx : 0.f;
                #pragma unroll
                for (int ct = 0; ct < 8; ++ct)
                    cs8[lrow][ct * 16 + l15] = (uchar)(__float2int_rn(vals[ct] * inv) + 128);
                if (l15 == 0 && row0 + lrow < n) scl[row0 + lrow] = s;
            }
        }
        __syncthreads();
        {
            int r = tid >> 1;
            int half = (tid & 1) * 64;
            if (row0 + r < n) {
                uint4* dstp = (uint4*)(hs8 + (size_t)(row0 + r) * 128 + half);
                const uint4* sp = (const uint4*)&cs8[r][half];
                #pragma unroll
                for (int q = 0; q < 4; ++q) dstp[q] = sp[q];
            }
        }
        return;
    }

    // ================= build path =================
    int* adjS  = (int*)smem;              // 49152 B
    int* indeg = (int*)(smem + 49152);    // 2048
    int* excl  = (int*)(smem + 51200);    // 2048
    int* shb   = (int*)(smem + 53248);    // 1024
    int* bt    = (int*)(smem + 54272);    // base/tot

    int b = blockIdx.x - ngemm;
    int nodebase = b << BSH;

    indeg[tid] = 0;
    indeg[tid + 256] = 0;
    __syncthreads();

    for (int run = tid; run < nblk1; run += 256) {
        const int* trow = tbl + run * (nbuck + 1);
        int s0 = trow[b], s1 = trow[b + 1];
        long base = (long)run * CE;
        for (int k = s0; k < s1; ++k) {
            uint pp = pairs[base + k];
            atomicAdd(&indeg[pp >> 17], 1);
        }
    }
    __syncthreads();

    int a0 = indeg[tid * 2];
    int a1 = indeg[tid * 2 + 1];
    shb[tid] = a0 + a1;
    __syncthreads();
    for (int off = 1; off < 256; off <<= 1) {
        int xv = (tid >= off) ? shb[tid - off] : 0;
        __syncthreads();
        if (tid >= off) shb[tid] += xv;
        __syncthreads();
    }
    int e0 = (tid == 0) ? 0 : shb[tid - 1];
    excl[tid * 2] = e0;
    excl[tid * 2 + 1] = e0 + a0;
    if (tid == 255) {
        bt[1] = shb[255];
        bt[0] = atomicAdd(gctr, shb[255]);
    }
    __syncthreads();
    int base = bt[0];
    int L = bt[1];

    int i0 = nodebase + tid * 2;
    if (i0 < n) {
        deg[i0] = a0 + 1;                       // + self-loop
        offs[i0] = base + excl[tid * 2];
        dis[i0] = rsqrtf((float)(a0 + 1));
    }
    if (i0 + 1 < n) {
        deg[i0 + 1] = a1 + 1;
        offs[i0 + 1] = base + excl[tid * 2 + 1];
        dis[i0 + 1] = rsqrtf((float)(a1 + 1));
    }
    indeg[tid] = 0;
    indeg[tid + 256] = 0;
    __syncthreads();

    if (L <= MAXW) {
        for (int run = tid; run < nblk1; run += 256) {
            const int* trow = tbl + run * (nbuck + 1);
            int s0 = trow[b], s1 = trow[b + 1];
            long pb = (long)run * CE;
            for (int k = s0; k < s1; ++k) {
                uint pp = pairs[pb + k];
                int local = pp >> 17;
                int pos = excl[local] + atomicAdd(&indeg[local], 1);
                adjS[pos] = (int)(pp & 0x1FFFFu);
            }
        }
        __syncthreads();
        for (int i = tid; i < L; i += 256) adj[base + i] = adjS[i];
    } else {
        for (int run = tid; run < nblk1; run += 256) {
            const int* trow = tbl + run * (nbuck + 1);
            int s0 = trow[b], s1 = trow[b + 1];
            long pb = (long)run * CE;
            for (int k = s0; k < s1; ++k) {
                uint pp = pairs[pb + k];
                int local = pp >> 17;
                int pos = base + excl[local] + atomicAdd(&indeg[local], 1);
                adj[pos] = (int)(pp & 0x1FFFFu);
            }
        }
    }
}

// ---------------- K3: scl *= dis (restores h*dis quantization semantics) -----

__global__ void k_fix(float* __restrict__ scl, const float* __restrict__ dis, int n) {
    int i = blockIdx.x * blockDim.x + threadIdx.x;
    if (i < n) scl[i] *= dis[i];
}

// ---------------- agg1: int8 gather (128 B/row), ubyte decode ----------------

__global__ __launch_bounds__(256) void k_agg1(
    const uchar* __restrict__ hs8, const float* __restrict__ scl,
    const float* __restrict__ dis, const int* __restrict__ offs,
    const int* __restrict__ deg, const int* __restrict__ adj,
    const float* __restrict__ b1, ushort* __restrict__ h1, int n) {
    int node = blockIdx.x * 4 + (threadIdx.x >> 6);
    if (node >= n) return;
    int lane = threadIdx.x & 63;
    int r = lane >> 4;
    int j = lane & 15;

    const uint2* hq = (const uint2*)hs8;   // row = 16 uint2
    int off = offs[node];
    int nsrc = deg[node];

    float a8[8] = {0.f, 0.f, 0.f, 0.f, 0.f, 0.f, 0.f, 0.f};
    float ss = 0.f;
    int i = r;
    #define ACC8(v, c)                                      \
        a8[0] += ub0((v).x) * (c); a8[1] += ub1((v).x) * (c); \
        a8[2] += ub2((v).x) * (c); a8[3] += ub3((v).x) * (c); \
        a8[4] += ub0((v).y) * (c); a8[5] += ub1((v).y) * (c); \
        a8[6] += ub2((v).y) * (c); a8[7] += ub3((v).y) * (c); \
        ss += (c);
    for (; i + 12 < nsrc; i += 16) {
        int s0 = (i == 0) ? node : adj[off + i - 1];
        int s1 = adj[off + i + 3];
        int s2 = adj[off + i + 7];
        int s3 = adj[off + i + 11];
        float c0 = scl[s0], c1 = scl[s1], c2 = scl[s2], c3 = scl[s3];
        uint2 v0 = hq[(size_t)s0 * 16 + j];
        uint2 v1 = hq[(size_t)s1 * 16 + j];
        uint2 v2 = hq[(size_t)s2 * 16 + j];
        uint2 v3 = hq[(size_t)s3 * 16 + j];
        ACC8(v0, c0) ACC8(v1, c1) ACC8(v2, c2) ACC8(v3, c3)
    }
    for (; i + 4 < nsrc; i += 8) {
        int s0 = (i == 0) ? node : adj[off + i - 1];
        int s1 = adj[off + i + 3];
        float c0 = scl[s0], c1 = scl[s1];
        uint2 v0 = hq[(size_t)s0 * 16 + j];
        uint2 v1 = hq[(size_t)s1 * 16 + j];
        ACC8(v0, c0) ACC8(v1, c1)
    }
    if (i < nsrc) {
        int s0 = (i == 0) ? node : adj[off + i - 1];
        float c0 = scl[s0];
        uint2 v0 = hq[(size_t)s0 * 16 + j];
        ACC8(v0, c0)
    }
    #undef ACC8
    #pragma unroll
    for (int q = 0; q < 8; ++q) {
        a8[q] += __shfl_xor(a8[q], 16);
        a8[q] += __shfl_xor(a8[q], 32);
    }
    ss += __shfl_xor(ss, 16);
    ss += __shfl_xor(ss, 32);
    float corr = 128.f * ss;
    #pragma unroll
    for (int q = 0; q < 8; ++q) a8[q] -= corr;

    float dv = dis[node];
    float4 ba = ((const float4*)b1)[j * 2];
    float4 bb = ((const float4*)b1)[j * 2 + 1];
    if (r == 0) {
        uint4 ov;
        ov.x = packbf(fmaxf(a8[0] * dv + ba.x, 0.f), fmaxf(a8[1] * dv + ba.y, 0.f));
        ov.y = packbf(fmaxf(a8[2] * dv + ba.z, 0.f), fmaxf(a8[3] * dv + ba.w, 0.f));
        ov.z = packbf(fmaxf(a8[4] * dv + bb.x, 0.f), fmaxf(a8[5] * dv + bb.y, 0.f));
        ov.w = packbf(fmaxf(a8[6] * dv + bb.z, 0.f), fmaxf(a8[7] * dv + bb.w, 0.f));
        ((uint4*)h1)[(size_t)node * 16 + j] = ov;
    }
}

// ---------------- GEMM2: h2q = int8( (h1 @ W2) * dis[row] ), per-row scale ----

__global__ __launch_bounds__(256) void k_gemm2(
    const ushort* __restrict__ h1, const float* __restrict__ W2,
    const float* __restrict__ dis, uchar* __restrict__ h2q,
    float* __restrict__ scl2, int n) {
    int t = blockIdx.x * blockDim.x + threadIdx.x;
    int row = t >> 3;
    int cg = t & 7;
    if (row >= n) return;
    const uint2* hr = (const uint2*)(h1 + (size_t)row * DH);
    const float4* w4 = (const float4*)W2;
    float4 acc = make_float4(0.f, 0.f, 0.f, 0.f);
    #pragma unroll 8
    for (int k4 = 0; k4 < DH / 4; ++k4) {
        uint2 au = hr[k4];
        float a0 = bf_lo(au.x), a1 = bf_hi(au.x), a2 = bf_lo(au.y), a3 = bf_hi(au.y);
        float4 w0 = w4[(k4 * 4 + 0) * 8 + cg];
        float4 w1 = w4[(k4 * 4 + 1) * 8 + cg];
        float4 w2 = w4[(k4 * 4 + 2) * 8 + cg];
        float4 w3 = w4[(k4 * 4 + 3) * 8 + cg];
        acc.x += a0 * w0.x + a1 * w1.x + a2 * w2.x + a3 * w3.x;
        acc.y += a0 * w0.y + a1 * w1.y + a2 * w2.y + a3 * w3.y;
        acc.z += a0 * w0.z + a1 * w1.z + a2 * w2.z + a3 * w3.z;
        acc.w += a0 * w0.w + a1 * w1.w + a2 * w2.w + a3 * w3.w;
    }
    float dv = dis[row];
    float vals[4] = {acc.x * dv, acc.y * dv, acc.z * dv, acc.w * dv};
    float mx = fmaxf(fmaxf(fabsf(vals[0]), fabsf(vals[1])),
                     fmaxf(fabsf(vals[2]), fabsf(vals[3])));
    mx = fmaxf(mx, __shfl_xor(mx, 1));
    mx = fmaxf(mx, __shfl_xor(mx, 2));
    mx = fmaxf(mx, __shfl_xor(mx, 4));
    float s = mx * (1.f / 127.f);
    float inv = (mx > 0.f) ? 127.f / mx : 0.f;
    uint q0 = (uint)(__float2int_rn(vals[0] * inv) + 128);
    uint q1 = (uint)(__float2int_rn(vals[1] * inv) + 128);
    uint q2 = (uint)(__float2int_rn(vals[2] * inv) + 128);
    uint q3 = (uint)(__float2int_rn(vals[3] * inv) + 128);
    ((uint*)h2q)[(size_t)row * 8 + cg] = q0 | (q1 << 8) | (q2 << 16) | (q3 << 24);
    if (cg == 0) scl2[row] = s;
}

// ---------------- agg2 (int8) + bias + log_softmax fused ----------------

__global__ __launch_bounds__(256) void k_agg2_lsm(
    const uchar* __restrict__ h2q, const float* __restrict__ scl2,
    const float* __restrict__ dis, const int* __restrict__ offs,
    const int* __restrict__ deg, const int* __restrict__ adj,
    const float* __restrict__ b2, float* __restrict__ out, int n) {
    int node = blockIdx.x * 8 + (threadIdx.x >> 5);
    if (node >= n) return;
    int t32 = threadIdx.x & 31;
    int rr = t32 >> 2;    // 0..7
    int j = t32 & 3;      // cols [j*8, j*8+8)

    const uint2* hq = (const uint2*)h2q;  // row = 4 uint2
    int off = offs[node];
    int nsrc = deg[node];

    float a8[8] = {0.f, 0.f, 0.f, 0.f, 0.f, 0.f, 0.f, 0.f};
    float ss = 0.f;
    int i = rr;
    #define ACC8(v, c)                                      \
        a8[0] += ub0((v).x) * (c); a8[1] += ub1((v).x) * (c); \
        a8[2] += ub2((v).x) * (c); a8[3] += ub3((v).x) * (c); \
        a8[4] += ub0((v).y) * (c); a8[5] += ub1((v).y) * (c); \
        a8[6] += ub2((v).y) * (c); a8[7] += ub3((v).y) * (c); \
        ss += (c);
    for (; i + 8 < nsrc; i += 16) {
        int s0 = (i == 0) ? node : adj[off + i - 1];
        int s1 = adj[off + i + 7];
        float c0 = scl2[s0], c1 = scl2[s1];
        uint2 v0 = hq[(size_t)s0 * 4 + j];
        uint2 v1 = hq[(size_t)s1 * 4 + j];
        ACC8(v0, c0) ACC8(v1, c1)
    }
    if (i < nsrc) {
        int s0 = (i == 0) ? node : adj[off + i - 1];
        float c0 = scl2[s0];
        uint2 v0 = hq[(size_t)s0 * 4 + j];
        ACC8(v0, c0)
    }
    #undef ACC8
    #pragma unroll
    for (int q = 0; q < 8; ++q) {
        a8[q] += __shfl_xor(a8[q], 4);
        a8[q] += __shfl_xor(a8[q], 8);
        a8[q] += __shfl_xor(a8[q], 16);
    }
    ss += __shfl_xor(ss, 4);
    ss += __shfl_xor(ss, 8);
    ss += __shfl_xor(ss, 16);
    float corr = 128.f * ss;
    #pragma unroll
    for (int q = 0; q < 8; ++q) a8[q] -= corr;

    float dv = dis[node];
    float4 ba = ((const float4*)b2)[j * 2];
    float4 bb = ((const float4*)b2)[j * 2 + 1];
    float v[8];
    v[0] = a8[0] * dv + ba.x; v[1] = a8[1] * dv + ba.y;
    v[2] = a8[2] * dv + ba.z; v[3] = a8[3] * dv + ba.w;
    v[4] = a8[4] * dv + bb.x; v[5] = a8[5] * dv + bb.y;
    v[6] = a8[6] * dv + bb.z; v[7] = a8[7] * dv + bb.w;
    float m = v[0];
    #pragma unroll
    for (int q = 1; q < 8; ++q) m = fmaxf(m, v[q]);
    m = fmaxf(m, __shfl_xor(m, 1));
    m = fmaxf(m, __shfl_xor(m, 2));
    float s = 0.f;
    #pragma unroll
    for (int q = 0; q < 8; ++q) s += __expf(v[q] - m);
    s += __shfl_xor(s, 1);
    s += __shfl_xor(s, 2);
    float ls = m + __logf(s);
    if (rr == 0) {
        float4 o0 = make_float4(v[0] - ls, v[1] - ls, v[2] - ls, v[3] - ls);
        float4 o1 = make_float4(v[4] - ls, v[5] - ls, v[6] - ls, v[7] - ls);
        float* op = out + (size_t)node * DOUT + j * 8;
        *(float4*)op = o0;
        *(float4*)(op + 4) = o1;
    }
}

extern "C" void kernel_launch(void* const* d_in, const int* in_sizes, int n_in,
                              void* d_out, int out_size, void* d_ws, size_t ws_size,
                              hipStream_t stream) {
    const float* x  = (const float*)d_in[0];
    const int*   ei = (const int*)d_in[1];
    const float* W1 = (const float*)d_in[2];
    const float* b1 = (const float*)d_in[3];
    const float* W2 = (const float*)d_in[4];
    const float* b2 = (const float*)d_in[5];
    int n = in_sizes[0] / DIN;
    int e = in_sizes[1] / 2;
    const int* src = ei;
    const int* dst = ei + e;
    float* out = (float*)d_out;

    int nblk1 = (e + CE - 1) / CE;          // partition blocks (391)
    int nbuck = (n + 511) >> BSH;           // 512-node buckets (196, <=256)
    int ngemm = (n + 127) / 128;            // gemm1 blocks (782)

    char* p = (char*)d_ws;
    uint*   pairs  = (uint*)p;    p += (size_t)e * 4;
    int*    tbl    = (int*)p;     p += (size_t)nblk1 * (nbuck + 1) * 4;
    int*    deg    = (int*)p;     p += (size_t)n * 4;
    int*    offs   = (int*)p;     p += (size_t)n * 4;
    int*    gctr   = (int*)p;     p += 1024;
    float*  dis    = (float*)p;   p += (size_t)n * 4;
    int*    adj    = (int*)p;     p += (size_t)e * 4;
    ushort* w1tg   = (ushort*)p;  p += (size_t)DIN * DH * 2;
    uchar*  hs8    = (uchar*)p;   p += (size_t)n * DH;
    float*  scl    = (float*)p;   p += (size_t)n * 4;
    ushort* h1     = (ushort*)p;  p += (size_t)n * DH * 2;
    uchar*  h2q    = (uchar*)p;   p += (size_t)n * DOUT;
    float*  scl2   = (float*)p;

    k_pre<<<nblk1 + 32, 256, 0, stream>>>(src, dst, pairs, tbl, gctr, W1, w1tg,
                                          e, nbuck, nblk1);
    k_bg<<<ngemm + nbuck, 256, 0, stream>>>(x, w1tg, hs8, scl,
                                            pairs, tbl, deg, offs, dis, adj, gctr,
                                            nblk1, nbuck, n, ngemm);
    k_fix<<<(n + 255) / 256, 256, 0, stream>>>(scl, dis, n);
    k_agg1<<<(n + 3) / 4, 256, 0, stream>>>(hs8, scl, dis, offs, deg, adj, b1, h1, n);
    k_gemm2<<<(n * 8 + 255) / 256, 256, 0, stream>>>(h1, W2, dis, h2q, scl2, n);
    k_agg2_lsm<<<(n + 7) / 8, 256, 0, stream>>>(h2q, scl2, dis, offs, deg, adj, b2, out, n);
}

// Round 29
// 224.905 us; speedup vs baseline: 1.0142x; 1.0142x over previous
//
#include <hip/hip_runtime.h>
#include <hip/hip_bf16.h>
#include <cstdint>

#define DIN 256
#define DH 128
#define DOUT 32
#define CE 4096          // edges per partition block (multiple of 256)
#define BSH 9            // bucket = 512-node window
#define MAXW 11264       // max adj window ints staged in LDS (44 KB)

typedef short s16x8 __attribute__((ext_vector_type(8)));
typedef float f32x4 __attribute__((ext_vector_type(4)));

__device__ inline ushort f2bf(float f) {          // used only in tiny prep
    uint u = __float_as_uint(f);
    u += 0x7fff + ((u >> 16) & 1);
    return (ushort)(u >> 16);
}
__device__ inline ushort cvtbf(float f) {         // compiler -> v_cvt_pk_bf16_f32
    __hip_bfloat16 b = __float2bfloat16(f);
    return __builtin_bit_cast(ushort, b);
}
__device__ inline float bf_lo(uint u) { return __uint_as_float(u << 16); }
__device__ inline float bf_hi(uint u) { return __uint_as_float(u & 0xffff0000u); }
__device__ inline uint packbf(float a, float b) {
    return (uint)cvtbf(a) | ((uint)cvtbf(b) << 16);
}
// compiler pattern-matches these to v_cvt_f32_ubyte0-3
__device__ inline float ub0(uint v) { return (float)(v & 0xFFu); }
__device__ inline float ub1(uint v) { return (float)((v >> 8) & 0xFFu); }
__device__ inline float ub2(uint v) { return (float)((v >> 16) & 0xFFu); }
__device__ inline float ub3(uint v) { return (float)(v >> 24); }

// ---------------- K1: part (blocks 0..nblk1-1)  ||  prep W1^T (last 32) ------

__global__ __launch_bounds__(256) void k_pre(
    const int* __restrict__ src, const int* __restrict__ dst,
    uint* __restrict__ pairs, int* __restrict__ tbl, int* __restrict__ gctr,
    const float* __restrict__ W1, ushort* __restrict__ w1tg,
    int e, int nbuck, int nblk1) {
    __shared__ int cnt[256];
    __shared__ int boffs[256];
    __shared__ int sh[256];
    __shared__ uint ps[CE];
    int tid = threadIdx.x;

    if (blockIdx.x >= nblk1) {   // ---- prep path: W1^T -> bf16 (64 KB)
        int o = (blockIdx.x - nblk1) * 1024 + tid * 4;
        int c = o >> 8;
        int k = o & 255;
        ushort4 v;
        v.x = f2bf(W1[(size_t)(k + 0) * DH + c]);
        v.y = f2bf(W1[(size_t)(k + 1) * DH + c]);
        v.z = f2bf(W1[(size_t)(k + 2) * DH + c]);
        v.w = f2bf(W1[(size_t)(k + 3) * DH + c]);
        *(ushort4*)(w1tg + o) = v;
        return;
    }

    // ---- part path: pack = (d&511)<<17 | s
    if (blockIdx.x == 0 && tid == 0) *gctr = 0;
    long blkbase = (long)blockIdx.x * CE;
    int ecnt = min(CE, (int)(e - blkbase));

    cnt[tid] = 0;
    __syncthreads();

    int dreg[CE / 256];
    #pragma unroll
    for (int k = 0; k < CE / 256; ++k) {
        int i = k * 256 + tid;
        int d = -1;
        if (i < ecnt) {
            d = dst[blkbase + i];
            atomicAdd(&cnt[d >> BSH], 1);
        }
        dreg[k] = d;
    }
    __syncthreads();
    sh[tid] = cnt[tid];
    __syncthreads();
    for (int off = 1; off < 256; off <<= 1) {
        int x = (tid >= off) ? sh[tid - off] : 0;
        __syncthreads();
        if (tid >= off) sh[tid] += x;
        __syncthreads();
    }
    boffs[tid] = (tid == 0) ? 0 : sh[tid - 1];
    cnt[tid] = 0;
    __syncthreads();
    #pragma unroll
    for (int k = 0; k < CE / 256; ++k) {
        int i = k * 256 + tid;
        if (i < ecnt) {
            int d = dreg[k];
            int b = d >> BSH;
            int slot = boffs[b] + atomicAdd(&cnt[b], 1);
            ps[slot] = ((uint)(d & 511) << 17) | (uint)src[blkbase + i];
        }
    }
    __syncthreads();
    for (int i = tid; i < ecnt; i += 256)
        pairs[blkbase + i] = ps[i];
    if (tid < nbuck) tbl[blockIdx.x * (nbuck + 1) + tid] = boffs[tid];
    if (tid == 0)    tbl[blockIdx.x * (nbuck + 1) + nbuck] = ecnt;
}

// ---------------- K2: build (blocks 0..nbuck-1)  ||  gemm1 (rest) ------------
// BUILD FIRST in grid order: the 196 latency-bound build blocks dispatch
// immediately and co-run with MFMA-heavy gemm blocks (separate pipes overlap).
// LDS union = 53248 B -> 3 blocks/CU.

__global__ __launch_bounds__(256) void k_bg(
    const float* __restrict__ x, const ushort* __restrict__ w1tg,
    uchar* __restrict__ hs8, float* __restrict__ scl,
    const uint* __restrict__ pairs, const int* __restrict__ tbl,
    int* __restrict__ deg, int* __restrict__ offs, float* __restrict__ dis,
    int* __restrict__ adj, int* __restrict__ gctr,
    int nblk1, int nbuck, int n) {
    __shared__ __align__(16) char smem[53248];
    int tid = threadIdx.x;

    if (blockIdx.x >= nbuck) {
        // ================= gemm1 path =================
        ushort (*w1t)[136] = (ushort(*)[136])smem;          // 34816 B
        uchar  (*cs8)[144] = (uchar(*)[144])smem;           // union
        ushort (*xs)[72]   = (ushort(*)[72])(smem + 34816); // 18432 B

        int row0 = (blockIdx.x - nbuck) * 128;
        int lane = tid & 63;
        int w = tid >> 6;
        int wr0 = w * 32;
        int l15 = lane & 15;
        int koff = (lane >> 4) * 8;

        f32x4 acc[2][8];
        #pragma unroll
        for (int i = 0; i < 2; ++i)
            #pragma unroll
            for (int j = 0; j < 8; ++j)
                acc[i][j] = (f32x4){0.f, 0.f, 0.f, 0.f};

        for (int kh = 0; kh < 2; ++kh) {
            {   // stage w1t half: pure vector copy
                int c = tid >> 1;
                int seg = (tid & 1) * 64;
                const uint4* gsrc = (const uint4*)(w1tg + (size_t)c * 256 + kh * 128 + seg);
                uint4* ldst = (uint4*)&w1t[c][seg];
                #pragma unroll
                for (int q = 0; q < 8; ++q) ldst[q] = gsrc[q];
            }
            for (int kc2 = 0; kc2 < 2; ++kc2) {
                {   // stage x tile (fp32 -> bf16 HW cvt)
                    int r = tid >> 1;
                    int half = (tid & 1) * 32;
                    int rr = row0 + r; if (rr >= n) rr = n - 1;
                    const float4* xr = (const float4*)(x + (size_t)rr * DIN + kh * 128 + kc2 * 64 + half);
                    float4 v[8];
                    #pragma unroll
                    for (int q = 0; q < 8; ++q) v[q] = xr[q];
                    #pragma unroll
                    for (int q = 0; q < 8; ++q) {
                        ushort4 o;
                        o.x = cvtbf(v[q].x); o.y = cvtbf(v[q].y);
                        o.z = cvtbf(v[q].z); o.w = cvtbf(v[q].w);
                        *(ushort4*)&xs[r][half + q * 4] = o;
                    }
                }
                __syncthreads();
                #pragma unroll
                for (int kk = 0; kk < 64; kk += 32) {
                    s16x8 a0 = *(const s16x8*)&xs[wr0 + l15][kk + koff];
                    s16x8 a1 = *(const s16x8*)&xs[wr0 + 16 + l15][kk + koff];
                    int kl = kc2 * 64 + kk + koff;
                    #pragma unroll
                    for (int ct = 0; ct < 8; ++ct) {
                        s16x8 b = *(const s16x8*)&w1t[ct * 16 + l15][kl];
                        acc[0][ct] = __builtin_amdgcn_mfma_f32_16x16x32_bf16(a0, b, acc[0][ct], 0, 0, 0);
                        acc[1][ct] = __builtin_amdgcn_mfma_f32_16x16x32_bf16(a1, b, acc[1][ct], 0, 0, 0);
                    }
                }
                __syncthreads();
            }
        }

        // quantize per row (NO dis — folded in later by k_fix)
        #pragma unroll
        for (int rt = 0; rt < 2; ++rt) {
            #pragma unroll
            for (int r = 0; r < 4; ++r) {
                int lrow = wr0 + rt * 16 + (lane >> 4) * 4 + r;
                float vals[8];
                float mx = 0.f;
                #pragma unroll
                for (int ct = 0; ct < 8; ++ct) {
                    vals[ct] = acc[rt][ct][r];
                    mx = fmaxf(mx, fabsf(vals[ct]));
                }
                mx = fmaxf(mx, __shfl_xor(mx, 1));
                mx = fmaxf(mx, __shfl_xor(mx, 2));
                mx = fmaxf(mx, __shfl_xor(mx, 4));
                mx = fmaxf(mx, __shfl_xor(mx, 8));
                float s = mx * (1.f / 127.f);
                float inv = (mx > 0.f) ? 127.f / mx : 0.f;
                #pragma unroll
                for (int ct = 0; ct < 8; ++ct)
                    cs8[lrow][ct * 16 + l15] = (uchar)(__float2int_rn(vals[ct] * inv) + 128);
                if (l15 == 0 && row0 + lrow < n) scl[row0 + lrow] = s;
            }
        }
        __syncthreads();
        {
            int r = tid >> 1;
            int half = (tid & 1) * 64;
            if (row0 + r < n) {
                uint4* dstp = (uint4*)(hs8 + (size_t)(row0 + r) * 128 + half);
                const uint4* sp = (const uint4*)&cs8[r][half];
                #pragma unroll
                for (int q = 0; q < 4; ++q) dstp[q] = sp[q];
            }
        }
        return;
    }

    // ================= build path =================
    int* adjS  = (int*)smem;              // 45056 B (MAXW ints)
    int* indeg = (int*)(smem + 45056);    // 2048
    int* excl  = (int*)(smem + 47104);    // 2048
    int* shb   = (int*)(smem + 49152);    // 1024
    int* bt    = (int*)(smem + 50176);    // base/tot

    int b = blockIdx.x;
    int nodebase = b << BSH;

    indeg[tid] = 0;
    indeg[tid + 256] = 0;
    __syncthreads();

    for (int run = tid; run < nblk1; run += 256) {
        const int* trow = tbl + run * (nbuck + 1);
        int s0 = trow[b], s1 = trow[b + 1];
        long base = (long)run * CE;
        for (int k = s0; k < s1; ++k) {
            uint pp = pairs[base + k];
            atomicAdd(&indeg[pp >> 17], 1);
        }
    }
    __syncthreads();

    int a0 = indeg[tid * 2];
    int a1 = indeg[tid * 2 + 1];
    shb[tid] = a0 + a1;
    __syncthreads();
    for (int off = 1; off < 256; off <<= 1) {
        int xv = (tid >= off) ? shb[tid - off] : 0;
        __syncthreads();
        if (tid >= off) shb[tid] += xv;
        __syncthreads();
    }
    int e0 = (tid == 0) ? 0 : shb[tid - 1];
    excl[tid * 2] = e0;
    excl[tid * 2 + 1] = e0 + a0;
    if (tid == 255) {
        bt[1] = shb[255];
        bt[0] = atomicAdd(gctr, shb[255]);
    }
    __syncthreads();
    int base = bt[0];
    int L = bt[1];

    int i0 = nodebase + tid * 2;
    if (i0 < n) {
        deg[i0] = a0 + 1;                       // + self-loop
        offs[i0] = base + excl[tid * 2];
        dis[i0] = rsqrtf((float)(a0 + 1));
    }
    if (i0 + 1 < n) {
        deg[i0 + 1] = a1 + 1;
        offs[i0 + 1] = base + excl[tid * 2 + 1];
        dis[i0 + 1] = rsqrtf((float)(a1 + 1));
    }
    indeg[tid] = 0;
    indeg[tid + 256] = 0;
    __syncthreads();

    if (L <= MAXW) {
        for (int run = tid; run < nblk1; run += 256) {
            const int* trow = tbl + run * (nbuck + 1);
            int s0 = trow[b], s1 = trow[b + 1];
            long pb = (long)run * CE;
            for (int k = s0; k < s1; ++k) {
                uint pp = pairs[pb + k];
                int local = pp >> 17;
                int pos = excl[local] + atomicAdd(&indeg[local], 1);
                adjS[pos] = (int)(pp & 0x1FFFFu);
            }
        }
        __syncthreads();
        for (int i = tid; i < L; i += 256) adj[base + i] = adjS[i];
    } else {
        for (int run = tid; run < nblk1; run += 256) {
            const int* trow = tbl + run * (nbuck + 1);
            int s0 = trow[b], s1 = trow[b + 1];
            long pb = (long)run * CE;
            for (int k = s0; k < s1; ++k) {
                uint pp = pairs[pb + k];
                int local = pp >> 17;
                int pos = base + excl[local] + atomicAdd(&indeg[local], 1);
                adj[pos] = (int)(pp & 0x1FFFFu);
            }
        }
    }
}

// ---------------- K3: scl *= dis (restores h*dis quantization semantics) -----

__global__ void k_fix(float* __restrict__ scl, const float* __restrict__ dis, int n) {
    int i = blockIdx.x * blockDim.x + threadIdx.x;
    if (i < n) scl[i] *= dis[i];
}

// ---------------- agg1: int8 gather (128 B/row), ubyte decode ----------------

__global__ __launch_bounds__(256) void k_agg1(
    const uchar* __restrict__ hs8, const float* __restrict__ scl,
    const float* __restrict__ dis, const int* __restrict__ offs,
    const int* __restrict__ deg, const int* __restrict__ adj,
    const float* __restrict__ b1, ushort* __restrict__ h1, int n) {
    int node = blockIdx.x * 4 + (threadIdx.x >> 6);
    if (node >= n) return;
    int lane = threadIdx.x & 63;
    int r = lane >> 4;
    int j = lane & 15;

    const uint2* hq = (const uint2*)hs8;   // row = 16 uint2
    int off = offs[node];
    int nsrc = deg[node];

    float a8[8] = {0.f, 0.f, 0.f, 0.f, 0.f, 0.f, 0.f, 0.f};
    float ss = 0.f;
    int i = r;
    #define ACC8(v, c)                                      \
        a8[0] += ub0((v).x) * (c); a8[1] += ub1((v).x) * (c); \
        a8[2] += ub2((v).x) * (c); a8[3] += ub3((v).x) * (c); \
        a8[4] += ub0((v).y) * (c); a8[5] += ub1((v).y) * (c); \
        a8[6] += ub2((v).y) * (c); a8[7] += ub3((v).y) * (c); \
        ss += (c);
    for (; i + 12 < nsrc; i += 16) {
        int s0 = (i == 0) ? node : adj[off + i - 1];
        int s1 = adj[off + i + 3];
        int s2 = adj[off + i + 7];
        int s3 = adj[off + i + 11];
        float c0 = scl[s0], c1 = scl[s1], c2 = scl[s2], c3 = scl[s3];
        uint2 v0 = hq[(size_t)s0 * 16 + j];
        uint2 v1 = hq[(size_t)s1 * 16 + j];
        uint2 v2 = hq[(size_t)s2 * 16 + j];
        uint2 v3 = hq[(size_t)s3 * 16 + j];
        ACC8(v0, c0) ACC8(v1, c1) ACC8(v2, c2) ACC8(v3, c3)
    }
    for (; i + 4 < nsrc; i += 8) {
        int s0 = (i == 0) ? node : adj[off + i - 1];
        int s1 = adj[off + i + 3];
        float c0 = scl[s0], c1 = scl[s1];
        uint2 v0 = hq[(size_t)s0 * 16 + j];
        uint2 v1 = hq[(size_t)s1 * 16 + j];
        ACC8(v0, c0) ACC8(v1, c1)
    }
    if (i < nsrc) {
        int s0 = (i == 0) ? node : adj[off + i - 1];
        float c0 = scl[s0];
        uint2 v0 = hq[(size_t)s0 * 16 + j];
        ACC8(v0, c0)
    }
    #undef ACC8
    #pragma unroll
    for (int q = 0; q < 8; ++q) {
        a8[q] += __shfl_xor(a8[q], 16);
        a8[q] += __shfl_xor(a8[q], 32);
    }
    ss += __shfl_xor(ss, 16);
    ss += __shfl_xor(ss, 32);
    float corr = 128.f * ss;
    #pragma unroll
    for (int q = 0; q < 8; ++q) a8[q] -= corr;

    float dv = dis[node];
    float4 ba = ((const float4*)b1)[j * 2];
    float4 bb = ((const float4*)b1)[j * 2 + 1];
    if (r == 0) {
        uint4 ov;
        ov.x = packbf(fmaxf(a8[0] * dv + ba.x, 0.f), fmaxf(a8[1] * dv + ba.y, 0.f));
        ov.y = packbf(fmaxf(a8[2] * dv + ba.z, 0.f), fmaxf(a8[3] * dv + ba.w, 0.f));
        ov.z = packbf(fmaxf(a8[4] * dv + bb.x, 0.f), fmaxf(a8[5] * dv + bb.y, 0.f));
        ov.w = packbf(fmaxf(a8[6] * dv + bb.z, 0.f), fmaxf(a8[7] * dv + bb.w, 0.f));
        ((uint4*)h1)[(size_t)node * 16 + j] = ov;
    }
}

// ---------------- GEMM2: h2q = int8( (h1 @ W2) * dis[row] ), per-row scale ----

__global__ __launch_bounds__(256) void k_gemm2(
    const ushort* __restrict__ h1, const float* __restrict__ W2,
    const float* __restrict__ dis, uchar* __restrict__ h2q,
    float* __restrict__ scl2, int n) {
    int t = blockIdx.x * blockDim.x + threadIdx.x;
    int row = t >> 3;
    int cg = t & 7;
    if (row >= n) return;
    const uint2* hr = (const uint2*)(h1 + (size_t)row * DH);
    const float4* w4 = (const float4*)W2;
    float4 acc = make_float4(0.f, 0.f, 0.f, 0.f);
    #pragma unroll 8
    for (int k4 = 0; k4 < DH / 4; ++k4) {
        uint2 au = hr[k4];
        float a0 = bf_lo(au.x), a1 = bf_hi(au.x), a2 = bf_lo(au.y), a3 = bf_hi(au.y);
        float4 w0 = w4[(k4 * 4 + 0) * 8 + cg];
        float4 w1 = w4[(k4 * 4 + 1) * 8 + cg];
        float4 w2 = w4[(k4 * 4 + 2) * 8 + cg];
        float4 w3 = w4[(k4 * 4 + 3) * 8 + cg];
        acc.x += a0 * w0.x + a1 * w1.x + a2 * w2.x + a3 * w3.x;
        acc.y += a0 * w0.y + a1 * w1.y + a2 * w2.y + a3 * w3.y;
        acc.z += a0 * w0.z + a1 * w1.z + a2 * w2.z + a3 * w3.z;
        acc.w += a0 * w0.w + a1 * w1.w + a2 * w2.w + a3 * w3.w;
    }
    float dv = dis[row];
    float vals[4] = {acc.x * dv, acc.y * dv, acc.z * dv, acc.w * dv};
    float mx = fmaxf(fmaxf(fabsf(vals[0]), fabsf(vals[1])),
                     fmaxf(fabsf(vals[2]), fabsf(vals[3])));
    mx = fmaxf(mx, __shfl_xor(mx, 1));
    mx = fmaxf(mx, __shfl_xor(mx, 2));
    mx = fmaxf(mx, __shfl_xor(mx, 4));
    float s = mx * (1.f / 127.f);
    float inv = (mx > 0.f) ? 127.f / mx : 0.f;
    uint q0 = (uint)(__float2int_rn(vals[0] * inv) + 128);
    uint q1 = (uint)(__float2int_rn(vals[1] * inv) + 128);
    uint q2 = (uint)(__float2int_rn(vals[2] * inv) + 128);
    uint q3 = (uint)(__float2int_rn(vals[3] * inv) + 128);
    ((uint*)h2q)[(size_t)row * 8 + cg] = q0 | (q1 << 8) | (q2 << 16) | (q3 << 24);
    if (cg == 0) scl2[row] = s;
}

// ---------------- agg2 (int8) + bias + log_softmax fused ----------------

__global__ __launch_bounds__(256) void k_agg2_lsm(
    const uchar* __restrict__ h2q, const float* __restrict__ scl2,
    const float* __restrict__ dis, const int* __restrict__ offs,
    const int* __restrict__ deg, const int* __restrict__ adj,
    const float* __restrict__ b2, float* __restrict__ out, int n) {
    int node = blockIdx.x * 8 + (threadIdx.x >> 5);
    if (node >= n) return;
    int t32 = threadIdx.x & 31;
    int rr = t32 >> 2;    // 0..7
    int j = t32 & 3;      // cols [j*8, j*8+8)

    const uint2* hq = (const uint2*)h2q;  // row = 4 uint2
    int off = offs[node];
    int nsrc = deg[node];

    float a8[8] = {0.f, 0.f, 0.f, 0.f, 0.f, 0.f, 0.f, 0.f};
    float ss = 0.f;
    int i = rr;
    #define ACC8(v, c)                                      \
        a8[0] += ub0((v).x) * (c); a8[1] += ub1((v).x) * (c); \
        a8[2] += ub2((v).x) * (c); a8[3] += ub3((v).x) * (c); \
        a8[4] += ub0((v).y) * (c); a8[5] += ub1((v).y) * (c); \
        a8[6] += ub2((v).y) * (c); a8[7] += ub3((v).y) * (c); \
        ss += (c);
    for (; i + 8 < nsrc; i += 16) {
        int s0 = (i == 0) ? node : adj[off + i - 1];
        int s1 = adj[off + i + 7];
        float c0 = scl2[s0], c1 = scl2[s1];
        uint2 v0 = hq[(size_t)s0 * 4 + j];
        uint2 v1 = hq[(size_t)s1 * 4 + j];
        ACC8(v0, c0) ACC8(v1, c1)
    }
    if (i < nsrc) {
        int s0 = (i == 0) ? node : adj[off + i - 1];
        float c0 = scl2[s0];
        uint2 v0 = hq[(size_t)s0 * 4 + j];
        ACC8(v0, c0)
    }
    #undef ACC8
    #pragma unroll
    for (int q = 0; q < 8; ++q) {
        a8[q] += __shfl_xor(a8[q], 4);
        a8[q] += __shfl_xor(a8[q], 8);
        a8[q] += __shfl_xor(a8[q], 16);
    }
    ss += __shfl_xor(ss, 4);
    ss += __shfl_xor(ss, 8);
    ss += __shfl_xor(ss, 16);
    float corr = 128.f * ss;
    #pragma unroll
    for (int q = 0; q < 8; ++q) a8[q] -= corr;

    float dv = dis[node];
    float4 ba = ((const float4*)b2)[j * 2];
    float4 bb = ((const float4*)b2)[j * 2 + 1];
    float v[8];
    v[0] = a8[0] * dv + ba.x; v[1] = a8[1] * dv + ba.y;
    v[2] = a8[2] * dv + ba.z; v[3] = a8[3] * dv + ba.w;
    v[4] = a8[4] * dv + bb.x; v[5] = a8[5] * dv + bb.y;
    v[6] = a8[6] * dv + bb.z; v[7] = a8[7] * dv + bb.w;
    float m = v[0];
    #pragma unroll
    for (int q = 1; q < 8; ++q) m = fmaxf(m, v[q]);
    m = fmaxf(m, __shfl_xor(m, 1));
    m = fmaxf(m, __shfl_xor(m, 2));
    float s = 0.f;
    #pragma unroll
    for (int q = 0; q < 8; ++q) s += __expf(v[q] - m);
    s += __shfl_xor(s, 1);
    s += __shfl_xor(s, 2);
    float ls = m + __logf(s);
    if (rr == 0) {
        float4 o0 = make_float4(v[0] - ls, v[1] - ls, v[2] - ls, v[3] - ls);
        float4 o1 = make_float4(v[4] - ls, v[5] - ls, v[6] - ls, v[7] - ls);
        float* op = out + (size_t)node * DOUT + j * 8;
        *(float4*)op = o0;
        *(float4*)(op + 4) = o1;
    }
}

extern "C" void kernel_launch(void* const* d_in, const int* in_sizes, int n_in,
                              void* d_out, int out_size, void* d_ws, size_t ws_size,
                              hipStream_t stream) {
    const float* x  = (const float*)d_in[0];
    const int*   ei = (const int*)d_in[1];
    const float* W1 = (const float*)d_in[2];
    const float* b1 = (const float*)d_in[3];
    const float* W2 = (const float*)d_in[4];
    const float* b2 = (const float*)d_in[5];
    int n = in_sizes[0] / DIN;
    int e = in_sizes[1] / 2;
    const int* src = ei;
    const int* dst = ei + e;
    float* out = (float*)d_out;

    int nblk1 = (e + CE - 1) / CE;          // partition blocks (391)
    int nbuck = (n + 511) >> BSH;           // 512-node buckets (196, <=256)
    int ngemm = (n + 127) / 128;            // gemm1 blocks (782)

    char* p = (char*)d_ws;
    uint*   pairs  = (uint*)p;    p += (size_t)e * 4;
    int*    tbl    = (int*)p;     p += (size_t)nblk1 * (nbuck + 1) * 4;
    int*    deg    = (int*)p;     p += (size_t)n * 4;
    int*    offs   = (int*)p;     p += (size_t)n * 4;
    int*    gctr   = (int*)p;     p += 1024;
    float*  dis    = (float*)p;   p += (size_t)n * 4;
    int*    adj    = (int*)p;     p += (size_t)e * 4;
    ushort* w1tg   = (ushort*)p;  p += (size_t)DIN * DH * 2;
    uchar*  hs8    = (uchar*)p;   p += (size_t)n * DH;
    float*  scl    = (float*)p;   p += (size_t)n * 4;
    ushort* h1     = (ushort*)p;  p += (size_t)n * DH * 2;
    uchar*  h2q    = (uchar*)p;   p += (size_t)n * DOUT;
    float*  scl2   = (float*)p;

    k_pre<<<nblk1 + 32, 256, 0, stream>>>(src, dst, pairs, tbl, gctr, W1, w1tg,
                                          e, nbuck, nblk1);
    k_bg<<<nbuck + ngemm, 256, 0, stream>>>(x, w1tg, hs8, scl,
                                            pairs, tbl, deg, offs, dis, adj, gctr,
                                            nblk1, nbuck, n);
    k_fix<<<(n + 255) / 256, 256, 0, stream>>>(scl, dis, n);
    k_agg1<<<(n + 3) / 4, 256, 0, stream>>>(hs8, scl, dis, offs, deg, adj, b1, h1, n);
    k_gemm2<<<(n * 8 + 255) / 256, 256, 0, stream>>>(h1, W2, dis, h2q, scl2, n);
    k_agg2_lsm<<<(n + 7) / 8, 256, 0, stream>>>(h2q, scl2, dis, offs, deg, adj, b2, out, n);
}